// Round 3
// baseline (247.115 us; speedup 1.0000x reference)
//
#include <hip/hip_runtime.h>

// ReactDiffDynamics, rolling-register stencil version.
// dUdt = a*lap(U)/dx^2 + U - U^3 - k - V ; dVdt = b*lap(V)/dx^2 + U - V
// Periodic 5-point Laplacian (jnp.roll), B=64, H=W=512, fp32.
// One block = one (batch, strip of R rows). 128 threads = one row of float4.
// prev/cur/next rows of U,V live in registers -> each x row fetched (R+2)/R times.

constexpr int B = 64;
constexpr int H = 512;
constexpr int W = 512;
constexpr int W4 = W / 4;        // 128 float4 per row
constexpr int PLANE = H * W;
constexpr int R = 8;             // rows per strip
constexpr int STRIPS = H / R;    // 64

typedef float vfloat4 __attribute__((ext_vector_type(4)));  // native vec for nontemporal store

__global__ __launch_bounds__(128) void react_diff_kernel(
    const float* __restrict__ x,       // (B, 2, H, W)
    const float* __restrict__ params,  // (B, 3)
    float* __restrict__ out)           // (B, 2, H, W)
{
    const float inv_dx2 = 240.25f;  // 1/dx^2, dx = 2/31

    const int wv = threadIdx.x;          // float4 column, 0..127
    const int s  = blockIdx.x % STRIPS;
    const int b  = blockIdx.x / STRIPS;
    const int h0 = s * R;

    const float* Ub = x + (size_t)b * 2 * PLANE;
    const float* Vb = Ub + PLANE;
    float*       Ob = out + (size_t)b * 2 * PLANE;

    const float pa = params[b * 3 + 0];
    const float pb = params[b * 3 + 1];
    const float pk = params[b * 3 + 2];

    const int w0 = wv * 4;
    const int wW = (wv == 0)      ? W - 1 : w0 - 1;   // west wrap
    const int wE = (wv == W4 - 1) ? 0     : w0 + 4;   // east wrap

    const int hp = (h0 == 0) ? H - 1 : h0 - 1;        // north halo row

    float4 Up = ((const float4*)(Ub + (size_t)hp * W))[wv];
    float4 Uc = ((const float4*)(Ub + (size_t)h0 * W))[wv];
    float4 Vp = ((const float4*)(Vb + (size_t)hp * W))[wv];
    float4 Vc = ((const float4*)(Vb + (size_t)h0 * W))[wv];

    #pragma unroll
    for (int r = 0; r < R; ++r) {
        const int h  = h0 + r;
        const int hn = (h + 1 == H) ? 0 : h + 1;      // south (wraps only on last strip)
        const size_t rc = (size_t)h  * W;
        const size_t rs = (size_t)hn * W;

        // issue all loads up front for ILP
        float4 Un = ((const float4*)(Ub + rs))[wv];
        float4 Vn = ((const float4*)(Vb + rs))[wv];
        float  Uw = Ub[rc + wW];
        float  Ue = Ub[rc + wE];
        float  Vw = Vb[rc + wW];
        float  Ve = Vb[rc + wE];

        float4 lapU, lapV;
        lapU.x = Up.x + Un.x + Uw   + Uc.y - 4.0f * Uc.x;
        lapU.y = Up.y + Un.y + Uc.x + Uc.z - 4.0f * Uc.y;
        lapU.z = Up.z + Un.z + Uc.y + Uc.w - 4.0f * Uc.z;
        lapU.w = Up.w + Un.w + Uc.z + Ue   - 4.0f * Uc.w;

        lapV.x = Vp.x + Vn.x + Vw   + Vc.y - 4.0f * Vc.x;
        lapV.y = Vp.y + Vn.y + Vc.x + Vc.z - 4.0f * Vc.y;
        lapV.z = Vp.z + Vn.z + Vc.y + Vc.w - 4.0f * Vc.z;
        lapV.w = Vp.w + Vn.w + Vc.z + Ve   - 4.0f * Vc.w;

        vfloat4 dU, dV;
        dU.x = pa * lapU.x * inv_dx2 + Uc.x - Uc.x * Uc.x * Uc.x - pk - Vc.x;
        dU.y = pa * lapU.y * inv_dx2 + Uc.y - Uc.y * Uc.y * Uc.y - pk - Vc.y;
        dU.z = pa * lapU.z * inv_dx2 + Uc.z - Uc.z * Uc.z * Uc.z - pk - Vc.z;
        dU.w = pa * lapU.w * inv_dx2 + Uc.w - Uc.w * Uc.w * Uc.w - pk - Vc.w;

        dV.x = pb * lapV.x * inv_dx2 + Uc.x - Vc.x;
        dV.y = pb * lapV.y * inv_dx2 + Uc.y - Vc.y;
        dV.z = pb * lapV.z * inv_dx2 + Uc.z - Vc.z;
        dV.w = pb * lapV.w * inv_dx2 + Uc.w - Vc.w;

        __builtin_nontemporal_store(dU, (vfloat4*)(Ob + rc) + wv);
        __builtin_nontemporal_store(dV, (vfloat4*)(Ob + PLANE + rc) + wv);

        Up = Uc; Uc = Un;
        Vp = Vc; Vc = Vn;
    }
}

extern "C" void kernel_launch(void* const* d_in, const int* in_sizes, int n_in,
                              void* d_out, int out_size, void* d_ws, size_t ws_size,
                              hipStream_t stream) {
    // d_in[0] = t (unused), d_in[1] = x (B,2,H,W) fp32, d_in[2] = params (B,3) fp32
    const float* x      = (const float*)d_in[1];
    const float* params = (const float*)d_in[2];
    float* out          = (float*)d_out;

    int grid = B * STRIPS;   // 4096 blocks, 128 threads each
    react_diff_kernel<<<grid, 128, 0, stream>>>(x, params, out);
}

// Round 4
// 233.112 us; speedup vs baseline: 1.0601x; 1.0601x over previous
//
#include <hip/hip_runtime.h>

// ReactDiffDynamics: dUdt = a*lap(U)+U-U^3-k-V ; dVdt = b*lap(V)+U-V, periodic 5pt.
// B=64, H=W=512 fp32. Massive-TLP layout: one thread per float4 (4.2M threads),
// XCD-aware block swizzle so north/south row reuse stays in the local 4MB L2,
// nontemporal stores so `out` doesn't evict `x` from L2/L3.
// HBM floor: 134MB read + 134MB write = 268MB ~= 40us @ 6.7 TB/s.

constexpr int B = 64;
constexpr int H = 512;
constexpr int W = 512;
constexpr int W4 = W / 4;          // 128 float4 per row
constexpr int PLANE = H * W;
constexpr int NXCD = 8;

typedef float vfloat4 __attribute__((ext_vector_type(4)));

__global__ __launch_bounds__(256) void react_diff_kernel(
    const float* __restrict__ x,       // (B, 2, H, W)
    const float* __restrict__ params,  // (B, 3)
    float* __restrict__ out)           // (B, 2, H, W)
{
    const float inv_dx2 = 240.25f;  // 1/dx^2

    // XCD swizzle: hardware round-robins blockIdx across 8 XCDs. Give XCD i the
    // contiguous slab [i*gridDim/8, ...) so adjacent rows are processed on the
    // same XCD and neighbor-row re-reads hit its L2.
    const int slab = gridDim.x / NXCD;                     // 2048
    const int eff  = (blockIdx.x % NXCD) * slab + blockIdx.x / NXCD;

    int tid = eff * 256 + threadIdx.x;   // [0, B*H*W4)
    int wv  = tid & (W4 - 1);
    int rem = tid >> 7;                  // /128
    int h   = rem & (H - 1);
    int b   = rem >> 9;                  // /512

    int hn = (h == 0)     ? H - 1 : h - 1;
    int hs = (h == H - 1) ? 0     : h + 1;
    int w0 = wv * 4;
    int wW = (wv == 0)      ? W - 1 : w0 - 1;
    int wE = (wv == W4 - 1) ? 0     : w0 + 4;

    const float* Ub = x + (size_t)b * 2 * PLANE;
    const float* Vb = Ub + PLANE;

    const size_t rc = (size_t)h  * W;
    const size_t rn = (size_t)hn * W;
    const size_t rs = (size_t)hs * W;

    vfloat4 Uc = ((const vfloat4*)(Ub + rc))[wv];
    vfloat4 Un = ((const vfloat4*)(Ub + rn))[wv];
    vfloat4 Us = ((const vfloat4*)(Ub + rs))[wv];
    float   Uw = Ub[rc + wW];
    float   Ue = Ub[rc + wE];

    vfloat4 Vc = ((const vfloat4*)(Vb + rc))[wv];
    vfloat4 Vn = ((const vfloat4*)(Vb + rn))[wv];
    vfloat4 Vs = ((const vfloat4*)(Vb + rs))[wv];
    float   Vw = Vb[rc + wW];
    float   Ve = Vb[rc + wE];

    float pa = params[b * 3 + 0];
    float pb = params[b * 3 + 1];
    float pk = params[b * 3 + 2];

    vfloat4 lapU, lapV;
    lapU.x = Un.x + Us.x + Uw   + Uc.y - 4.0f * Uc.x;
    lapU.y = Un.y + Us.y + Uc.x + Uc.z - 4.0f * Uc.y;
    lapU.z = Un.z + Us.z + Uc.y + Uc.w - 4.0f * Uc.z;
    lapU.w = Un.w + Us.w + Uc.z + Ue   - 4.0f * Uc.w;

    lapV.x = Vn.x + Vs.x + Vw   + Vc.y - 4.0f * Vc.x;
    lapV.y = Vn.y + Vs.y + Vc.x + Vc.z - 4.0f * Vc.y;
    lapV.z = Vn.z + Vs.z + Vc.y + Vc.w - 4.0f * Vc.z;
    lapV.w = Vn.w + Vs.w + Vc.z + Ve   - 4.0f * Vc.w;

    vfloat4 dU, dV;
    dU.x = pa * lapU.x * inv_dx2 + Uc.x - Uc.x * Uc.x * Uc.x - pk - Vc.x;
    dU.y = pa * lapU.y * inv_dx2 + Uc.y - Uc.y * Uc.y * Uc.y - pk - Vc.y;
    dU.z = pa * lapU.z * inv_dx2 + Uc.z - Uc.z * Uc.z * Uc.z - pk - Vc.z;
    dU.w = pa * lapU.w * inv_dx2 + Uc.w - Uc.w * Uc.w * Uc.w - pk - Vc.w;

    dV.x = pb * lapV.x * inv_dx2 + Uc.x - Vc.x;
    dV.y = pb * lapV.y * inv_dx2 + Uc.y - Vc.y;
    dV.z = pb * lapV.z * inv_dx2 + Uc.z - Vc.z;
    dV.w = pb * lapV.w * inv_dx2 + Uc.w - Vc.w;

    float* ob = out + (size_t)b * 2 * PLANE;
    __builtin_nontemporal_store(dU, (vfloat4*)(ob + rc) + wv);
    __builtin_nontemporal_store(dV, (vfloat4*)(ob + PLANE + rc) + wv);
}

extern "C" void kernel_launch(void* const* d_in, const int* in_sizes, int n_in,
                              void* d_out, int out_size, void* d_ws, size_t ws_size,
                              hipStream_t stream) {
    // d_in[0] = t (unused), d_in[1] = x (B,2,H,W) fp32, d_in[2] = params (B,3) fp32
    const float* x      = (const float*)d_in[1];
    const float* params = (const float*)d_in[2];
    float* out          = (float*)d_out;

    int total_vec = B * H * W4;            // 4,194,304 threads
    int grid = total_vec / 256;            // 16384 blocks
    react_diff_kernel<<<grid, 256, 0, stream>>>(x, params, out);
}